// Round 5
// baseline (87.052 us; speedup 1.0000x reference)
//
#include <hip/hip_runtime.h>

// x: [B=32, C=128, H=128, W=128] f32
// out: [B, 3C, 64, 64] f32 — [vals | pos_h | pos_w] along channel dim.
// K=2 pool + argmax position decode (first-max ties, row-major window order).
//
// Wave-tile: 4 consecutive input rows (2 output rows) per iteration.
//   2x dwordx4 NT loads, each 1024 B contiguous across the wave
//   __shfl_xor(.,32) redistributes rows so lanes 0-31 own output row 2*oh01,
//   lanes 32-63 own row 2*oh01+1
//   3x dwordx2 NT stores, each 512 B contiguous
// Grid: 2048 blocks = 8192 waves = full residency (32 waves/CU) in ONE round.
// Stride 8192 makes oh01 loop-invariant and all address increments constant.

typedef float f32x4 __attribute__((ext_vector_type(4)));
typedef float f32x2 __attribute__((ext_vector_type(2)));

__global__ __launch_bounds__(256) void pap_kernel(const float* __restrict__ x,
                                                  float* __restrict__ out) {
    constexpr int C = 128, H = 128, W = 128;
    constexpr int OH = 64, OW = 64;
    constexpr float inv = 1.0f / 128.0f;
    constexpr size_t plane = (size_t)C * OH * OW;      // 524288 floats
    constexpr int NITER = 16;                          // 131072 tiles / 8192 waves
    constexpr size_t IN_STEP  = (size_t)256 * H * W;   // bc += 256 per iter
    constexpr size_t OUT_STEP = (size_t)2 * 3 * C * OH * OW;  // b += 2 per iter

    const int lane = threadIdx.x & 63;
    const int wid  = (blockIdx.x * blockDim.x + threadIdx.x) >> 6;  // 0..8191
    const bool hi  = lane >= 32;
    const int j    = lane & 31;

    const int oh01 = wid & 31;           // invariant output row pair
    const int bc0  = wid >> 5;           // 0..255
    const int b0   = bc0 >> 7, c0 = bc0 & (C - 1);
    const int oh_out = 2 * oh01 + (hi ? 1 : 0);

    size_t base = (size_t)bc0 * (H * W) + (size_t)oh01 * (4 * W) + lane * 4;
    size_t orow = ((size_t)(b0 * (3 * C) + c0)) * (OH * OW)
                + (size_t)oh_out * OW + 2 * j;

    const float ph_lo = (float)(2 * oh_out) * inv;       // idx>>1 == 0
    const float ph_hi = (float)(2 * oh_out + 1) * inv;   // idx>>1 == 1
    const float pw0_lo = (float)(4 * j) * inv,     pw0_hi = (float)(4 * j + 1) * inv;
    const float pw1_lo = (float)(4 * j + 2) * inv, pw1_hi = (float)(4 * j + 3) * inv;

    #pragma unroll 4
    for (int k = 0; k < NITER; ++k) {
        f32x4 la = __builtin_nontemporal_load(reinterpret_cast<const f32x4*>(x + base));
        f32x4 lb = __builtin_nontemporal_load(reinterpret_cast<const f32x4*>(x + base + 2 * W));

        float top[4], bot[4];
        #pragma unroll
        for (int e = 0; e < 4; ++e) {
            const float sa = __shfl_xor(la[e], 32, 64);
            const float sb = __shfl_xor(lb[e], 32, 64);
            top[e] = hi ? sb : la[e];
            bot[e] = hi ? lb[e] : sa;
        }

        f32x2 vals, ph, pw;
        {   // window 0: order top0,top1,bot0,bot1
            float v = top[0]; int idx = 0;
            if (top[1] > v) { v = top[1]; idx = 1; }
            if (bot[0] > v) { v = bot[0]; idx = 2; }
            if (bot[1] > v) { v = bot[1]; idx = 3; }
            vals.x = v;
            ph.x = (idx & 2) ? ph_hi : ph_lo;
            pw.x = (idx & 1) ? pw0_hi : pw0_lo;
        }
        {   // window 1
            float v = top[2]; int idx = 0;
            if (top[3] > v) { v = top[3]; idx = 1; }
            if (bot[2] > v) { v = bot[2]; idx = 2; }
            if (bot[3] > v) { v = bot[3]; idx = 3; }
            vals.y = v;
            ph.y = (idx & 2) ? ph_hi : ph_lo;
            pw.y = (idx & 1) ? pw1_hi : pw1_lo;
        }

        __builtin_nontemporal_store(vals, reinterpret_cast<f32x2*>(out + orow));
        __builtin_nontemporal_store(ph,   reinterpret_cast<f32x2*>(out + orow + plane));
        __builtin_nontemporal_store(pw,   reinterpret_cast<f32x2*>(out + orow + 2 * plane));

        base += IN_STEP;
        orow += OUT_STEP;
    }
}

extern "C" void kernel_launch(void* const* d_in, const int* in_sizes, int n_in,
                              void* d_out, int out_size, void* d_ws, size_t ws_size,
                              hipStream_t stream) {
    const float* x = (const float*)d_in[0];
    float* out = (float*)d_out;
    pap_kernel<<<2048, 256, 0, stream>>>(x, out);
}

// Round 7
// 77.238 us; speedup vs baseline: 1.1271x; 1.1271x over previous
//
#include <hip/hip_runtime.h>

// x: [B=32, C=128, H=128, W=128] f32
// out: [B, 3C, 64, 64] f32 — [vals | pos_h | pos_w] along channel dim.
// K=2 pool + argmax position decode (first-max ties, row-major window order).
//
// Wave-tile structure (best measured: 82.8 us, 5.67 TB/s effective):
//   one wave-iteration = 4 consecutive input rows (2 output rows)
//   2x dwordx4 NT loads, each 1024 B contiguous across the wave
//   __shfl_xor(.,32) redistributes rows: lanes 0-31 -> output row 2*oh01,
//   lanes 32-63 -> 2*oh01+1
//   3x dwordx2 stores, each 512 B contiguous
// NOTE: stores are intentionally NOT nontemporal. R6 (NT stores) flaked the
// post-timing revalidation with one output line left at harness poison —
// consistent with a weakly-ordered nt store line not visible to the D2H read.
// NT loads are safe: input is read-only and never mutated.

typedef float f32x4 __attribute__((ext_vector_type(4)));
typedef float f32x2 __attribute__((ext_vector_type(2)));

__global__ __launch_bounds__(256) void pap_kernel(const float* __restrict__ x,
                                                  float* __restrict__ out) {
    constexpr int C = 128, H = 128, W = 128;
    constexpr int OH = 64, OW = 64;
    constexpr float inv = 1.0f / 128.0f;
    constexpr int NTILES = 32 * C * (OH / 2);   // 131072 wave-tiles
    constexpr size_t plane = (size_t)C * OH * OW;  // 524288 floats

    const int lane = threadIdx.x & 63;
    const int wid  = (blockIdx.x * blockDim.x + threadIdx.x) >> 6;
    const int nw   = (gridDim.x * blockDim.x) >> 6;
    const bool hi  = lane >= 32;
    const int j    = lane & 31;

    for (int t = wid; t < NTILES; t += nw) {
        const int oh01 = t & 31;          // output row pair 0..31
        const int bc   = t >> 5;          // b*C + c, 0..4095

        const size_t base = (size_t)bc * (H * W) + (size_t)oh01 * (4 * W) + lane * 4;
        f32x4 la = __builtin_nontemporal_load(reinterpret_cast<const f32x4*>(x + base));
        f32x4 lb = __builtin_nontemporal_load(reinterpret_cast<const f32x4*>(x + base + 2 * W));

        // lanes 0-31 of la = quad row0, lanes 32-63 = row1; lb: rows 2,3
        float top[4], bot[4];
        #pragma unroll
        for (int k = 0; k < 4; ++k) {
            const float sa = __shfl_xor(la[k], 32, 64);   // partner's la
            const float sb = __shfl_xor(lb[k], 32, 64);   // partner's lb
            top[k] = hi ? sb : la[k];   // lo: row0 chunk, hi: row2 chunk
            bot[k] = hi ? lb[k] : sa;   // lo: row1 chunk, hi: row3 chunk
        }

        const int oh_out = 2 * oh01 + (hi ? 1 : 0);
        f32x2 vals, ph, pw;
        {   // window 0: cols 4j,4j+1 — order top0,top1,bot0,bot1
            float v = top[0]; int idx = 0;
            if (top[1] > v) { v = top[1]; idx = 1; }
            if (bot[0] > v) { v = bot[0]; idx = 2; }
            if (bot[1] > v) { v = bot[1]; idx = 3; }
            vals.x = v;
            ph.x = (float)(2 * oh_out + (idx >> 1)) * inv;
            pw.x = (float)(4 * j + (idx & 1)) * inv;
        }
        {   // window 1: cols 4j+2,4j+3
            float v = top[2]; int idx = 0;
            if (top[3] > v) { v = top[3]; idx = 1; }
            if (bot[2] > v) { v = bot[2]; idx = 2; }
            if (bot[3] > v) { v = bot[3]; idx = 3; }
            vals.y = v;
            ph.y = (float)(2 * oh_out + (idx >> 1)) * inv;
            pw.y = (float)(4 * j + 2 + (idx & 1)) * inv;
        }

        const int b_ = bc >> 7, c = bc & (C - 1);
        const size_t orow = ((size_t)(b_ * (3 * C) + c)) * (OH * OW)
                          + (size_t)oh_out * OW + 2 * j;
        *reinterpret_cast<f32x2*>(out + orow)             = vals;
        *reinterpret_cast<f32x2*>(out + orow + plane)     = ph;
        *reinterpret_cast<f32x2*>(out + orow + 2 * plane) = pw;
    }
}

extern "C" void kernel_launch(void* const* d_in, const int* in_sizes, int n_in,
                              void* d_out, int out_size, void* d_ws, size_t ws_size,
                              hipStream_t stream) {
    const float* x = (const float*)d_in[0];
    float* out = (float*)d_out;
    const int blocks = 4096;   // 16384 waves; 131072 tiles -> 8 tiles/wave exact
    pap_kernel<<<blocks, 256, 0, stream>>>(x, out);
}